// Round 1
// baseline (185.824 us; speedup 1.0000x reference)
//
#include <hip/hip_runtime.h>

// DropBlock, fully fused single kernel — v2.
// out[n,c,h,w] = x[n,c,h,w] * block_mask[h,w] * scale
// block_mask = 1 - maxpool7x7_backward(u < gamma); scale = HW / sum(block_mask)
//
// v2 changes vs v1 (180.9 us total, kernel ~58 us):
//  * NBLOCKS = 2009 (divisible by 49) => STRIDE = 514304 = 656*784, so each
//    thread's multiplier index p = t % 784 is LOOP-INVARIANT. The multiplier
//    is one vfloat4 in registers; inner loop is pure load-mul-store
//    (no LDS read, no modular arithmetic). Unrolled x2 for 2 loads in flight.
//  * Prologue rebuilt: __ballot packs 64 seed bits per wave-instruction
//    (was: byte array + 56 serial ds_read_u8 per lane); H-dilation via
//    __shfl_up (no rowdil LDS, no wave_barrier); scale via __shfl_xor
//    butterfly (was: thread-0 serial 56-load loop). 2 barriers, ~0.9 KB LDS.
//  * First two x float4s prefetched BEFORE the prologue — mask-latency
//    hides under useful HBM traffic.
//  * Plain loads/stores (nontemporal dropped): matches the 6.29 TB/s
//    measured float4-copy pattern.

#define HW      3136   // 56*56
#define WDIM    56
#define HDIM    56
#define HW4     784    // HW/4 float4s per (n,c) plane
#define ROWMASK 0x00FFFFFFFFFFFFFFull  // low 56 bits
#define NBLOCKS 2009u                  // 49*41: STRIDE % 784 == 0
#define STRIDE  (NBLOCKS * 256u)       // 514304

typedef float vfloat4 __attribute__((ext_vector_type(4)));

__global__ void __launch_bounds__(256) dropblock_fused_kernel(
        const float* __restrict__ u, const vfloat4* __restrict__ x,
        vfloat4* __restrict__ out, unsigned int nvec) {
    __shared__ unsigned long long chunks[49];    // 3136 seed bits
    __shared__ unsigned long long dropbits[HDIM];
    __shared__ float s_scale;

    // gamma exactly as Python float64 arithmetic, then cast to f32
    const float gamma = (float)(0.1 / 49.0 * (3136.0 / 2500.0));

    const unsigned int t = blockIdx.x * 256u + threadIdx.x;

    // Prefetch the first pair of x vectors; completes while the mask
    // prologue runs. (t + STRIDE = max 1,028,607 < nvec = 6,422,528.)
    vfloat4 a0 = x[t];
    vfloat4 a1 = x[t + STRIDE];

    const int lane = threadIdx.x & 63;
    const int wave = threadIdx.x >> 6;

    // Phase 1: seed bits via ballot — wave w, round k covers elements
    // [256k + 64w, 256k + 64w + 64). Coalesced 4B u loads (L2/L3 hits).
    #pragma unroll
    for (int k = 0; k < 12; ++k) {
        unsigned long long b = __ballot(u[k * 256 + threadIdx.x] < gamma);
        if (lane == 0) chunks[4 * k + wave] = b;
    }
    if (wave == 0) {  // last 64 elements: 3072..3135
        unsigned long long b = __ballot(u[3072 + lane] < gamma);
        if (lane == 0) chunks[48] = b;
    }
    __syncthreads();

    // Phase 2: one wave. Lane r: extract row r (56 bits), W-dilate (<<0..6),
    // H-dilate via shfl_up over rows r-6..r, then butterfly-reduce kept count.
    if (wave == 0) {
        const int r = lane;
        unsigned long long rd = 0ull;
        if (r < HDIM) {
            int bit = r * WDIM;
            int a = bit >> 6, off = bit & 63;   // off in {0,8,16,...,56}
            unsigned long long row = chunks[a] >> off;
            if (off > 8) row |= chunks[a + 1] << (64 - off); // a+1 <= 48
            row &= ROWMASK;
            rd = row;
            #pragma unroll
            for (int k = 1; k < 7; ++k) rd |= row << k;
            rd &= ROWMASK;
        }
        // Backward-looking H-window: OR of rd from lanes r-6..r.
        // (__shfl_up keeps own value for lanes < k — harmless, idempotent OR.)
        unsigned long long d = rd;
        #pragma unroll
        for (int k = 1; k <= 6; ++k)
            d |= __shfl_up(rd, k);
        int kept = 0;
        if (r < HDIM) {
            dropbits[r] = d;
            kept = WDIM - __popcll(d);
        }
        #pragma unroll
        for (int s = 32; s; s >>= 1) kept += __shfl_xor(kept, s);
        if (lane == 0) s_scale = (float)HW / (float)kept;  // exact small-int
    }
    __syncthreads();

    // Phase 3: loop-invariant register multiplier. q = t % 784 never changes
    // across grid-stride iterations because STRIDE % 784 == 0.
    {
        const unsigned int q = t % (unsigned int)HW4;
        const int r = (int)q / 14;              // 14 float4 per 56-wide row
        const int c0 = ((int)q - r * 14) * 4;
        const unsigned long long d = dropbits[r];
        const float scale = s_scale;
        vfloat4 m;
        m[0] = ((d >> c0) & 1ull) ? 0.0f : scale;
        m[1] = ((d >> (c0 + 1)) & 1ull) ? 0.0f : scale;
        m[2] = ((d >> (c0 + 2)) & 1ull) ? 0.0f : scale;
        m[3] = ((d >> (c0 + 3)) & 1ull) ? 0.0f : scale;

        // Phase 4: pure streaming multiply, 2 loads in flight per wave.
        out[t] = a0 * m;
        out[t + STRIDE] = a1 * m;
        unsigned int i = t + 2u * STRIDE;
        for (; i + STRIDE < nvec; i += 2u * STRIDE) {
            vfloat4 b0 = x[i];
            vfloat4 b1 = x[i + STRIDE];
            out[i] = b0 * m;
            out[i + STRIDE] = b1 * m;
        }
        if (i < nvec) out[i] = x[i] * m;        // odd 13th element
    }
}

extern "C" void kernel_launch(void* const* d_in, const int* in_sizes, int n_in,
                              void* d_out, int out_size, void* d_ws, size_t ws_size,
                              hipStream_t stream) {
    const float* x = (const float*)d_in[0];   // (32,256,56,56) fp32
    const float* u = (const float*)d_in[1];   // (56,56) fp32
    float* out = (float*)d_out;

    unsigned int nvec = (unsigned int)(out_size / 4);   // 6,422,528 float4s
    dropblock_fused_kernel<<<NBLOCKS, 256, 0, stream>>>(
        u, (const vfloat4*)x, (vfloat4*)out, nvec);
}

// Round 2
// 184.816 us; speedup vs baseline: 1.0055x; 1.0055x over previous
//
#include <hip/hip_runtime.h>

// DropBlock, fully fused single kernel — v3.
// out[n,c,h,w] = x[n,c,h,w] * block_mask[h,w] * scale
// block_mask = 1 - maxpool7x7_backward(u < gamma); scale = HW / sum(block_mask)
//
// v3 changes vs v2 (kernel 65.5 us, 2.35 TB/s HBM — latency-limited, not BW):
//  * Streaming phase FULLY UNROLLED dataflow-style: each thread has exactly
//    12 or 13 float4s (STRIDE=514304, nvec=6,422,528 = 12*STRIDE + 250,880).
//    Loads issue in groups of 4, with group k+1's loads issued BEFORE group
//    k's stores — vmcnt retires in order, so the stores' waits never block
//    younger loads: 4-8 x 1KB loads in flight per wave (v2 had 2).
//  * u loaded into registers BEFORE the x prefetch, so the ballot's waitcnt
//    does not drain the prefetch loads.
//  * Nontemporal stores restored (write-once stream; preserves x in L3).
//  * __launch_bounds__(256, 8) pins 8 waves/SIMD (VGPR <= 64).
// Kept from v2: NBLOCKS=2009 (49*41) => STRIDE % 784 == 0 => per-thread
// multiplier is ONE loop-invariant vfloat4 in registers; ballot/shfl mask
// prologue (~1 KB LDS, 2 barriers).

#define HW      3136   // 56*56
#define WDIM    56
#define HDIM    56
#define HW4     784    // HW/4 float4s per (n,c) plane
#define ROWMASK 0x00FFFFFFFFFFFFFFull  // low 56 bits
#define NBLOCKS 2009u                  // 49*41: STRIDE % 784 == 0
#define STRIDE  514304u                // NBLOCKS*256 = 784*656
#define NVEC    6422528u               // 32*256*784 float4s
#define REM     250880u                // NVEC - 12*STRIDE: threads < REM do 13

typedef float vfloat4 __attribute__((ext_vector_type(4)));

__global__ void __launch_bounds__(256, 8) dropblock_fused_kernel(
        const float* __restrict__ u, const vfloat4* __restrict__ x,
        vfloat4* __restrict__ out) {
    __shared__ unsigned long long chunks[49];    // 3136 seed bits
    __shared__ unsigned long long dropbits[HDIM];
    __shared__ float s_scale;

    // gamma exactly as Python float64 arithmetic, then cast to f32
    const float gamma = (float)(0.1 / 49.0 * (3136.0 / 2500.0));

    const unsigned int t = blockIdx.x * 256u + threadIdx.x;
    const int lane = threadIdx.x & 63;
    const int wave = threadIdx.x >> 6;

    // --- u loads first (oldest in vmcnt queue: the ballot waits drain ONLY
    // these, not the x prefetch issued after) ---
    float u0  = u[threadIdx.x];
    float u1  = u[threadIdx.x + 256];
    float u2  = u[threadIdx.x + 512];
    float u3  = u[threadIdx.x + 768];
    float u4  = u[threadIdx.x + 1024];
    float u5  = u[threadIdx.x + 1280];
    float u6  = u[threadIdx.x + 1536];
    float u7  = u[threadIdx.x + 1792];
    float u8  = u[threadIdx.x + 2048];
    float u9  = u[threadIdx.x + 2304];
    float u10 = u[threadIdx.x + 2560];
    float u11 = u[threadIdx.x + 2816];
    float ulast = 0.0f;
    if (wave == 0) ulast = u[3072 + lane];       // elements 3072..3135

    // --- prefetch first load-group of the stream (hides under prologue) ---
    vfloat4 a0 = x[t];
    vfloat4 a1 = x[t + STRIDE];
    vfloat4 a2 = x[t + 2u * STRIDE];
    vfloat4 a3 = x[t + 3u * STRIDE];

    // Phase 1: seed bits via ballot — wave w, chunk 4k+w covers elements
    // [256k + 64w, 256k + 64w + 64).
    {
        unsigned long long b;
        b = __ballot(u0  < gamma); if (lane == 0) chunks[ 0 + wave] = b;
        b = __ballot(u1  < gamma); if (lane == 0) chunks[ 4 + wave] = b;
        b = __ballot(u2  < gamma); if (lane == 0) chunks[ 8 + wave] = b;
        b = __ballot(u3  < gamma); if (lane == 0) chunks[12 + wave] = b;
        b = __ballot(u4  < gamma); if (lane == 0) chunks[16 + wave] = b;
        b = __ballot(u5  < gamma); if (lane == 0) chunks[20 + wave] = b;
        b = __ballot(u6  < gamma); if (lane == 0) chunks[24 + wave] = b;
        b = __ballot(u7  < gamma); if (lane == 0) chunks[28 + wave] = b;
        b = __ballot(u8  < gamma); if (lane == 0) chunks[32 + wave] = b;
        b = __ballot(u9  < gamma); if (lane == 0) chunks[36 + wave] = b;
        b = __ballot(u10 < gamma); if (lane == 0) chunks[40 + wave] = b;
        b = __ballot(u11 < gamma); if (lane == 0) chunks[44 + wave] = b;
        if (wave == 0) {
            b = __ballot(ulast < gamma);
            if (lane == 0) chunks[48] = b;
        }
    }
    __syncthreads();

    // Phase 2: one wave. Lane r: extract row r (56 bits), W-dilate (<<0..6),
    // H-dilate via shfl_up over rows r-6..r, butterfly-reduce kept count.
    if (wave == 0) {
        const int r = lane;
        unsigned long long rd = 0ull;
        if (r < HDIM) {
            int bit = r * WDIM;
            int a = bit >> 6, off = bit & 63;   // off in {0,8,...,56}
            unsigned long long row = chunks[a] >> off;
            if (off > 8) row |= chunks[a + 1] << (64 - off); // a+1 <= 48
            row &= ROWMASK;
            rd = row;
            #pragma unroll
            for (int k = 1; k < 7; ++k) rd |= row << k;
            rd &= ROWMASK;
        }
        unsigned long long d = rd;
        #pragma unroll
        for (int k = 1; k <= 6; ++k)
            d |= __shfl_up(rd, k);              // lanes<k keep own: idempotent
        int kept = 0;
        if (r < HDIM) {
            dropbits[r] = d;
            kept = WDIM - __popcll(d);
        }
        #pragma unroll
        for (int s = 32; s; s >>= 1) kept += __shfl_xor(kept, s);
        if (lane == 0) s_scale = (float)HW / (float)kept;  // exact small-int
    }
    __syncthreads();

    // Phase 3: loop-invariant register multiplier (q = t % 784 fixed since
    // STRIDE % 784 == 0).
    vfloat4 m;
    {
        const unsigned int q = t % (unsigned int)HW4;
        const int r = (int)q / 14;              // 14 float4 per 56-wide row
        const int c0 = ((int)q - r * 14) * 4;
        const unsigned long long d = dropbits[r];
        const float scale = s_scale;
        m[0] = ((d >> c0) & 1ull) ? 0.0f : scale;
        m[1] = ((d >> (c0 + 1)) & 1ull) ? 0.0f : scale;
        m[2] = ((d >> (c0 + 2)) & 1ull) ? 0.0f : scale;
        m[3] = ((d >> (c0 + 3)) & 1ull) ? 0.0f : scale;
    }

    // Phase 4: fully-unrolled software-pipelined stream (12 or 13 elements).
    // Issue order: loads(group k+1) BEFORE stores(group k) — in-order vmcnt
    // retirement means the store waits never block the younger loads.
    const bool ht = t < REM;                    // 13th element?

    // group B loads (a-group already in flight)
    vfloat4 b0 = x[t + 4u * STRIDE];
    vfloat4 b1 = x[t + 5u * STRIDE];
    vfloat4 b2 = x[t + 6u * STRIDE];
    vfloat4 b3 = x[t + 7u * STRIDE];
    // group A stores
    __builtin_nontemporal_store(a0 * m, &out[t]);
    __builtin_nontemporal_store(a1 * m, &out[t + STRIDE]);
    __builtin_nontemporal_store(a2 * m, &out[t + 2u * STRIDE]);
    __builtin_nontemporal_store(a3 * m, &out[t + 3u * STRIDE]);
    // group C loads
    vfloat4 c0 = x[t + 8u * STRIDE];
    vfloat4 c1 = x[t + 9u * STRIDE];
    vfloat4 c2 = x[t + 10u * STRIDE];
    vfloat4 c3 = x[t + 11u * STRIDE];
    vfloat4 d0;
    if (ht) d0 = x[t + 12u * STRIDE];
    // group B stores
    __builtin_nontemporal_store(b0 * m, &out[t + 4u * STRIDE]);
    __builtin_nontemporal_store(b1 * m, &out[t + 5u * STRIDE]);
    __builtin_nontemporal_store(b2 * m, &out[t + 6u * STRIDE]);
    __builtin_nontemporal_store(b3 * m, &out[t + 7u * STRIDE]);
    // group C stores
    __builtin_nontemporal_store(c0 * m, &out[t + 8u * STRIDE]);
    __builtin_nontemporal_store(c1 * m, &out[t + 9u * STRIDE]);
    __builtin_nontemporal_store(c2 * m, &out[t + 10u * STRIDE]);
    __builtin_nontemporal_store(c3 * m, &out[t + 11u * STRIDE]);
    if (ht) __builtin_nontemporal_store(d0 * m, &out[t + 12u * STRIDE]);
}

extern "C" void kernel_launch(void* const* d_in, const int* in_sizes, int n_in,
                              void* d_out, int out_size, void* d_ws, size_t ws_size,
                              hipStream_t stream) {
    const float* x = (const float*)d_in[0];   // (32,256,56,56) fp32
    const float* u = (const float*)d_in[1];   // (56,56) fp32
    float* out = (float*)d_out;

    // out_size/16 == NVEC (6,422,528 float4s) — compile-time constant layout.
    dropblock_fused_kernel<<<NBLOCKS, 256, 0, stream>>>(
        u, (const vfloat4*)x, (vfloat4*)out);
}

// Round 3
// 182.347 us; speedup vs baseline: 1.0191x; 1.0135x over previous
//
#include <hip/hip_runtime.h>

// DropBlock, fully fused single kernel — v4.
// out[n,c,h,w] = x[n,c,h,w] * block_mask[h,w] * scale
// block_mask = 1 - maxpool7x7_backward(u < gamma); scale = HW / sum(block_mask)
//
// v4 theory (vmcnt mixed-queue serialization): VMEM ops retire IN ORDER in
// one queue. Any structure that issues stores between a load's issue and its
// consumption forces every load-consume wait to also drain all older stores
// (v1/v2/v3 all did this -> all stuck at ~3.3 TB/s app BW, half of the
// 6.29 TB/s copy ceiling; meanwhile fillBuffer hits 6.6 TB/s at 9% occupancy,
// so depth/occupancy was never the limiter).
// Fix: per-thread work = exactly 4 float4s; ALL loads issue BEFORE the mask
// prologue (pinned with sched_barrier(0)); the prologue's __syncthreads
// drains them for free; stores issue at the very end. No load ever waits on
// a store anywhere in the kernel.
//  * threads = 12544*128 = 1,605,632 (6272 blocks x 256): multiple of both
//    256 and 784 -> per-thread multiplier q = t % 784 still loop-invariant
//    (ONE vfloat4 in registers); nvec = 4*threads exactly -> no remainder.
//  * nt stores (write-once stream), plain loads (keep x L3-resident across
//    bench iterations; FETCH_SIZE=50MB shows L3 supplies half the reads).

#define HW      3136   // 56*56
#define WDIM    56
#define HDIM    56
#define HW4     784    // HW/4 float4s per (n,c) plane
#define ROWMASK 0x00FFFFFFFFFFFFFFull  // low 56 bits
#define NB      6272u                  // blocks
#define NT      1605632u               // NB*256 = 12544*128; NT % 784 == 0
#define NVEC    6422528u               // 32*256*784 = 4*NT exactly

typedef float vfloat4 __attribute__((ext_vector_type(4)));

__global__ void __launch_bounds__(256, 8) dropblock_fused_kernel(
        const float* __restrict__ u, const vfloat4* __restrict__ x,
        vfloat4* __restrict__ out) {
    __shared__ unsigned long long chunks[49];    // 3136 seed bits
    __shared__ unsigned long long dropbits[HDIM];
    __shared__ float s_scale;

    // gamma exactly as Python float64 arithmetic, then cast to f32
    const float gamma = (float)(0.1 / 49.0 * (3136.0 / 2500.0));

    const unsigned int t = blockIdx.x * 256u + threadIdx.x;
    const int lane = threadIdx.x & 63;
    const int wave = threadIdx.x >> 6;

    // --- u loads first (oldest in the vmcnt queue: ballot waits drain only
    // these, not the x loads issued after) ---
    float u0  = u[threadIdx.x];
    float u1  = u[threadIdx.x + 256];
    float u2  = u[threadIdx.x + 512];
    float u3  = u[threadIdx.x + 768];
    float u4  = u[threadIdx.x + 1024];
    float u5  = u[threadIdx.x + 1280];
    float u6  = u[threadIdx.x + 1536];
    float u7  = u[threadIdx.x + 1792];
    float u8  = u[threadIdx.x + 2048];
    float u9  = u[threadIdx.x + 2304];
    float u10 = u[threadIdx.x + 2560];
    float u11 = u[threadIdx.x + 2816];
    float ulast = 0.0f;
    if (wave == 0) ulast = u[3072 + lane];       // elements 3072..3135

    // --- ALL x loads for this thread, issued before any store exists.
    // They complete under the prologue; the __syncthreads drain is free. ---
    vfloat4 a0 = x[t];
    vfloat4 a1 = x[t + NT];
    vfloat4 a2 = x[t + 2u * NT];
    vfloat4 a3 = x[t + 3u * NT];
    // Pin issue order: keep these loads ABOVE the prologue (compiler may not
    // sink them past this point).
    __builtin_amdgcn_sched_barrier(0);

    // Phase 1: seed bits via ballot — wave w, chunk 4k+w covers elements
    // [256k + 64w, 256k + 64w + 64).
    {
        unsigned long long b;
        b = __ballot(u0  < gamma); if (lane == 0) chunks[ 0 + wave] = b;
        b = __ballot(u1  < gamma); if (lane == 0) chunks[ 4 + wave] = b;
        b = __ballot(u2  < gamma); if (lane == 0) chunks[ 8 + wave] = b;
        b = __ballot(u3  < gamma); if (lane == 0) chunks[12 + wave] = b;
        b = __ballot(u4  < gamma); if (lane == 0) chunks[16 + wave] = b;
        b = __ballot(u5  < gamma); if (lane == 0) chunks[20 + wave] = b;
        b = __ballot(u6  < gamma); if (lane == 0) chunks[24 + wave] = b;
        b = __ballot(u7  < gamma); if (lane == 0) chunks[28 + wave] = b;
        b = __ballot(u8  < gamma); if (lane == 0) chunks[32 + wave] = b;
        b = __ballot(u9  < gamma); if (lane == 0) chunks[36 + wave] = b;
        b = __ballot(u10 < gamma); if (lane == 0) chunks[40 + wave] = b;
        b = __ballot(u11 < gamma); if (lane == 0) chunks[44 + wave] = b;
        if (wave == 0) {
            b = __ballot(ulast < gamma);
            if (lane == 0) chunks[48] = b;
        }
    }
    __syncthreads();

    // Phase 2: one wave. Lane r: extract row r (56 bits), W-dilate (<<0..6),
    // H-dilate via shfl_up over rows r-6..r, butterfly-reduce kept count.
    if (wave == 0) {
        const int r = lane;
        unsigned long long rd = 0ull;
        if (r < HDIM) {
            int bit = r * WDIM;
            int a = bit >> 6, off = bit & 63;   // off in {0,8,...,56}
            unsigned long long row = chunks[a] >> off;
            if (off > 8) row |= chunks[a + 1] << (64 - off); // a+1 <= 48
            row &= ROWMASK;
            rd = row;
            #pragma unroll
            for (int k = 1; k < 7; ++k) rd |= row << k;
            rd &= ROWMASK;
        }
        unsigned long long d = rd;
        #pragma unroll
        for (int k = 1; k <= 6; ++k)
            d |= __shfl_up(rd, k);              // lanes<k keep own: idempotent
        int kept = 0;
        if (r < HDIM) {
            dropbits[r] = d;
            kept = WDIM - __popcll(d);
        }
        #pragma unroll
        for (int s = 32; s; s >>= 1) kept += __shfl_xor(kept, s);
        if (lane == 0) s_scale = (float)HW / (float)kept;  // exact small-int
    }
    __syncthreads();

    // Phase 3: loop-invariant register multiplier (q = t % 784 fixed since
    // NT % 784 == 0).
    vfloat4 m;
    {
        const unsigned int q = t % (unsigned int)HW4;
        const int r = (int)q / 14;              // 14 float4 per 56-wide row
        const int c0 = ((int)q - r * 14) * 4;
        const unsigned long long d = dropbits[r];
        const float scale = s_scale;
        m[0] = ((d >> c0) & 1ull) ? 0.0f : scale;
        m[1] = ((d >> (c0 + 1)) & 1ull) ? 0.0f : scale;
        m[2] = ((d >> (c0 + 2)) & 1ull) ? 0.0f : scale;
        m[3] = ((d >> (c0 + 3)) & 1ull) ? 0.0f : scale;
    }

    // Phase 4: stores only. Loads were all forced complete by the barriers;
    // no vmcnt wait ever blocks on a store. Fire-and-forget, then exit.
    __builtin_nontemporal_store(a0 * m, &out[t]);
    __builtin_nontemporal_store(a1 * m, &out[t + NT]);
    __builtin_nontemporal_store(a2 * m, &out[t + 2u * NT]);
    __builtin_nontemporal_store(a3 * m, &out[t + 3u * NT]);
}

extern "C" void kernel_launch(void* const* d_in, const int* in_sizes, int n_in,
                              void* d_out, int out_size, void* d_ws, size_t ws_size,
                              hipStream_t stream) {
    const float* x = (const float*)d_in[0];   // (32,256,56,56) fp32
    const float* u = (const float*)d_in[1];   // (56,56) fp32
    float* out = (float*)d_out;

    // out_size/16 == NVEC (6,422,528 float4s) == 4*NT — compile-time layout.
    dropblock_fused_kernel<<<NB, 256, 0, stream>>>(
        u, (const vfloat4*)x, (vfloat4*)out);
}